// Round 14
// baseline (15.399 us; speedup 1.0000x reference)
//
#include <hip/hip_runtime.h>
#include <math.h>

// ---- problem constants ----
// SIZE=(60,270,480); CHANNELS=14; GRIDS: (60,16,16,8),(30,8,8,4),(15,4,4,2)
// IDX_MAX=(60,3,5) -> patch=(1,90,96); PADDING=(0,1,1) -> ppad=(1,92,98)
// t_embed: [64][1][92][98][14] = 8,078,336 f32 ; t_manip: [64][16]

#define N_PATCH 64
#define PPAD_H 92
#define PPAD_W 98
#define CH 14
#define PIX_PER_PATCH (PPAD_H * PPAD_W)        // 9016
#define ROWS_PER_BLOCK 2
#define BLOCKS_PER_PATCH 46
#define PX_PER_BLOCK 196
#define F4_PER_BLOCK (PX_PER_BLOCK * CH / 4)   // 686
#define ELEMS_PER_PATCH (PIX_PER_PATCH * CH)   // 126224
#define ELEMS_PER_BLOCK (PX_PER_BLOCK * CH)    // 2744
#define TOTAL_EMBED (N_PATCH * ELEMS_PER_PATCH)
#define TOTAL_MANIP (N_PATCH * 16)

// V-record per row (floats): L0 [0,48)=6cells*8ch, L1 [48,64)=4*4, L2 [64,70)=3*2
#define RB_STRIDE 72
#define L1_OFF 48
#define L2_OFF 64
// BASE/DIF slot tables per row: L0 5slots*8=40 @0, L1 3*4=12 @40, L2 2*2=4 @52
#define BD_L1 40
#define BD_L2 52
#define BD_COUNT 56
#define BD_STRIDE 64

#define SW0 ((float)((double)16 / 480.0))
#define SW1 ((float)((double)8  / 480.0))
#define SW2 ((float)((double)4  / 480.0))
#define SH0 ((float)((double)16 / 270.0))
#define SH1 ((float)((double)8  / 270.0))
#define SH2 ((float)((double)4  / 270.0))

__device__ __forceinline__ float lerpf(float a, float b, float f) {
    return a + f * (b - a);
}

// unclamped leftmost w-cell index (w0 of rw0)
__device__ __forceinline__ int wcell0u(int rw0, float sw) {
    float x = ((float)rw0 + 0.5f) * sw - 0.5f;
    return (int)floorf(x);
}

__global__ __launch_bounds__(256) void embed_kernel(
    const int* __restrict__ idx,
    const float* __restrict__ g0,
    const float* __restrict__ g1,
    const float* __restrict__ g2,
    float* __restrict__ out)
{
    __shared__ __align__(16) float s_V[ROWS_PER_BLOCK][RB_STRIDE];   // 576 B
    __shared__ __align__(16) float s_B[ROWS_PER_BLOCK][BD_STRIDE];   // 512 B
    __shared__ __align__(16) float s_D[ROWS_PER_BLOCK][BD_STRIDE];   // 512 B
    __shared__ __align__(16) float s_buf[PX_PER_BLOCK * CH];         // 11 KB

    const int tid = threadIdx.x;
    const int bx  = blockIdx.x;
    const int n   = blockIdx.y;
    const int it  = idx[3 * n + 0];
    const int ih  = idx[3 * n + 1];
    const int iw  = idx[3 * n + 2];
    const int rw0 = iw * 96 - 1;

    const int C0u0 = wcell0u(rw0, SW0);
    const int C0u1 = wcell0u(rw0, SW1);
    const int C0u2 = wcell0u(rw0, SW2);
    const int C0_0 = min(max(C0u0, 0), 15);
    const int C0_1 = min(max(C0u1, 0), 7);
    const int C0_2 = min(max(C0u2, 0), 3);

    // ---- fused manip (one block only) ----
    if (bx == 0 && n == 0) {
        float* om = out + TOTAL_EMBED;
        for (int e = tid; e < TOTAL_MANIP; e += 256) {
            int nn = e >> 4;
            int j  = e & 15;
            int l  = j & 7;
            float base = (float)M_PI * (float)(1 << l);  // fl32(2^l*pi), pow2 exact
            float v = (float)idx[3 * nn + 0] * base;     // f32 mul = reference
            double dv = (double)v;
            om[e] = (float)((j < 8) ? sin(dv) : cos(dv));
        }
    }

    // ---- stage 1: V tables (h,t-lerped, row-mask folded), 140 entries ----
    if (tid < 96) {
        int chn  = tid & 7;
        int u    = tid >> 3;
        int row  = (u >= 6);
        int cell = u - 6 * row;
        int rh   = ih * 90 + (bx * 2 + row) - 1;
        float mh = ((unsigned)rh < 270u) ? 1.0f : 0.0f;
        float xh = ((float)rh + 0.5f) * SH0 - 0.5f;
        float ff = floorf(xh);
        float fh = xh - ff;
        int h0 = (int)ff;
        int h0c = min(max(h0, 0), 15), h1c = min(h0 + 1, 15);
        int cw = min(C0_0 + cell, 15);
        const float* base = g0 + (size_t)it * 2048;
        float a = base[(h0c * 16 + cw) * 8 + chn];
        float b = base[(h1c * 16 + cw) * 8 + chn];
        s_V[row][cell * 8 + chn] = mh * lerpf(a, b, fh);
    } else if (tid < 128) {
        int i    = tid - 96;
        int chn  = i & 3;
        int u    = i >> 2;
        int row  = (u >= 4);
        int cell = u - 4 * row;
        int rh   = ih * 90 + (bx * 2 + row) - 1;
        float mh = ((unsigned)rh < 270u) ? 1.0f : 0.0f;
        float xh = ((float)rh + 0.5f) * SH1 - 0.5f;
        float ff = floorf(xh);
        float fh = xh - ff;
        int h0 = (int)ff;
        int h0c = min(max(h0, 0), 7), h1c = min(h0 + 1, 7);
        float xt = ((float)it + 0.5f) * 0.5f - 0.5f;     // 30/60 exact
        float ftf = floorf(xt);
        float ft  = xt - ftf;
        int t0 = (int)ftf;
        int t0c = min(max(t0, 0), 29), t1c = min(t0 + 1, 29);
        int cw = min(C0_1 + cell, 7);
        float a00 = g1[((t0c * 8 + h0c) * 8 + cw) * 4 + chn];
        float a01 = g1[((t0c * 8 + h1c) * 8 + cw) * 4 + chn];
        float a10 = g1[((t1c * 8 + h0c) * 8 + cw) * 4 + chn];
        float a11 = g1[((t1c * 8 + h1c) * 8 + cw) * 4 + chn];
        s_V[row][L1_OFF + cell * 4 + chn] =
            mh * lerpf(lerpf(a00, a01, fh), lerpf(a10, a11, fh), ft);
    } else if (tid < 140) {
        int i    = tid - 128;
        int chn  = i & 1;
        int u    = i >> 1;
        int row  = (u >= 3);
        int cell = u - 3 * row;
        int rh   = ih * 90 + (bx * 2 + row) - 1;
        float mh = ((unsigned)rh < 270u) ? 1.0f : 0.0f;
        float xh = ((float)rh + 0.5f) * SH2 - 0.5f;
        float ff = floorf(xh);
        float fh = xh - ff;
        int h0 = (int)ff;
        int h0c = min(max(h0, 0), 3), h1c = min(h0 + 1, 3);
        float xt = ((float)it + 0.5f) * 0.25f - 0.5f;    // 15/60 exact
        float ftf = floorf(xt);
        float ft  = xt - ftf;
        int t0 = (int)ftf;
        int t0c = min(max(t0, 0), 14), t1c = min(t0 + 1, 14);
        int cw = min(C0_2 + cell, 3);
        float a00 = g2[((t0c * 4 + h0c) * 4 + cw) * 2 + chn];
        float a01 = g2[((t0c * 4 + h1c) * 4 + cw) * 2 + chn];
        float a10 = g2[((t1c * 4 + h0c) * 4 + cw) * 2 + chn];
        float a11 = g2[((t1c * 4 + h1c) * 4 + cw) * 2 + chn];
        s_V[row][L2_OFF + cell * 2 + chn] =
            mh * lerpf(lerpf(a00, a01, fh), lerpf(a10, a11, fh), ft);
    }
    __syncthreads();

    // ---- stage 1.5: BASE/DIF slot tables (clamping baked in), 224 entries ----
    if (tid < 2 * 2 * BD_COUNT) {
        int row = tid >= 2 * BD_COUNT;
        int o   = tid - 2 * BD_COUNT * row;
        int d   = o >= BD_COUNT;            // 0 = BASE, 1 = DIF
        int k   = o - BD_COUNT * d;
        int lvl, s0, chn, cs, vb, C0u, C0c, Wg1;
        if (k < BD_L1)      { lvl = 0; s0 = k >> 3; chn = k & 7;
                              cs = 8; vb = 0;      C0u = C0u0; C0c = C0_0; Wg1 = 15; }
        else if (k < BD_L2) { int kk = k - BD_L1; lvl = 1; s0 = kk >> 2; chn = kk & 3;
                              cs = 4; vb = L1_OFF; C0u = C0u1; C0c = C0_1; Wg1 = 7; }
        else                { int kk = k - BD_L2; lvl = 2; s0 = kk >> 1; chn = kk & 1;
                              cs = 2; vb = L2_OFF; C0u = C0u2; C0c = C0_2; Wg1 = 3; }
        (void)lvl;
        int w0 = C0u + s0;                       // unclamped cell for this slot
        int wa = min(max(w0, 0), Wg1);
        int wb = min(w0 + 1, Wg1);
        float va = s_V[row][vb + (wa - C0c) * cs + chn];
        float vbv = s_V[row][vb + (wb - C0c) * cs + chn];
        if (d == 0) s_B[row][k] = va;
        else        s_D[row][k] = vbv - va;      // the sub, hoisted out of pixel loop
    }
    __syncthreads();

    // ---- stage 2: per-pixel, clamp-free fma-only channels ----
    if (tid < PX_PER_BLOCK) {
        int row = (tid >= PPAD_W);
        int ww  = tid - PPAD_W * row;
        int rw  = iw * 96 + ww - 1;
        float2* b = (float2*)(s_buf + tid * CH);

        if (rw == -1 || rw == 480) {
            float2 z = make_float2(0.f, 0.f);
            b[0] = z; b[1] = z; b[2] = z; b[3] = z; b[4] = z; b[5] = z; b[6] = z;
        } else {
            float rwc = (float)rw + 0.5f;

            float x0 = rwc * SW0 - 0.5f;
            float f0f = floorf(x0);
            float fw0 = x0 - f0f;
            int s00 = (int)f0f - C0u0;           // in [0,4]
            float x1 = rwc * SW1 - 0.5f;
            float f1f = floorf(x1);
            float fw1 = x1 - f1f;
            int s01 = (int)f1f - C0u1;           // in [0,2]
            float x2 = rwc * SW2 - 0.5f;
            float f2f = floorf(x2);
            float fw2 = x2 - f2f;
            int s02 = (int)f2f - C0u2;           // in [0,1]

            const float* B = s_B[row];
            const float* D = s_D[row];
            float4 B0 = *(const float4*)(B + s00 * 8);
            float4 B1 = *(const float4*)(B + s00 * 8 + 4);
            float4 D0 = *(const float4*)(D + s00 * 8);
            float4 D1 = *(const float4*)(D + s00 * 8 + 4);
            float4 Bc = *(const float4*)(B + BD_L1 + s01 * 4);
            float4 Dc = *(const float4*)(D + BD_L1 + s01 * 4);
            float2 Be = *(const float2*)(B + BD_L2 + s02 * 2);
            float2 De = *(const float2*)(D + BD_L2 + s02 * 2);

            b[0] = make_float2(fmaf(fw0, D0.x, B0.x), fmaf(fw0, D0.y, B0.y));
            b[1] = make_float2(fmaf(fw0, D0.z, B0.z), fmaf(fw0, D0.w, B0.w));
            b[2] = make_float2(fmaf(fw0, D1.x, B1.x), fmaf(fw0, D1.y, B1.y));
            b[3] = make_float2(fmaf(fw0, D1.z, B1.z), fmaf(fw0, D1.w, B1.w));
            b[4] = make_float2(fmaf(fw1, Dc.x, Bc.x), fmaf(fw1, Dc.y, Bc.y));
            b[5] = make_float2(fmaf(fw1, Dc.z, Bc.z), fmaf(fw1, Dc.w, Bc.w));
            b[6] = make_float2(fmaf(fw2, De.x, Be.x), fmaf(fw2, De.y, Be.y));
        }
    }
    __syncthreads();

    // ---- stage 3: coalesced store, unrolled (686 f4, 16B-aligned base) ----
    const float4* sb = (const float4*)s_buf;
    float4* gb = (float4*)(out + (size_t)n * ELEMS_PER_PATCH + bx * ELEMS_PER_BLOCK);
    gb[tid]       = sb[tid];
    gb[tid + 256] = sb[tid + 256];
    if (tid < F4_PER_BLOCK - 512) gb[tid + 512] = sb[tid + 512];
}

extern "C" void kernel_launch(void* const* d_in, const int* in_sizes, int n_in,
                              void* d_out, int out_size, void* d_ws, size_t ws_size,
                              hipStream_t stream) {
    const int*   idx = (const int*)  d_in[0];
    const float* g0  = (const float*)d_in[3];
    const float* g1  = (const float*)d_in[4];
    const float* g2  = (const float*)d_in[5];
    float* out = (float*)d_out;

    dim3 grid(BLOCKS_PER_PATCH, N_PATCH);   // (46, 64) = 2944 blocks
    embed_kernel<<<grid, 256, 0, stream>>>(idx, g0, g1, g2, out);
}